// Round 1
// baseline (39.921 us; speedup 1.0000x reference)
//
#include <hip/hip_runtime.h>

// RouteExactNgramMemory forward.
// Shapes: B=2, T=1024, HIDDEN=1024, BITS=4, R=256 routes, ALPHABET=16,
// MEM_DIM=16, NGRAMS=(2,3).
// out[b,t,o,r,d] flat = [B, T, 2*256*16] f32.

#define BB 2
#define TT 1024
#define RR 256
#define DD 16

// Pass 1: pack sign bits of 4 consecutive logits into a 4-bit code.
// q viewed as float4[B*T*R]; tid indexes it directly.
__global__ void codes_kernel(const float* __restrict__ q,
                             unsigned char* __restrict__ codes) {
    int tid = blockIdx.x * blockDim.x + threadIdx.x;   // [0, B*T*R)
    float4 v = reinterpret_cast<const float4*>(q)[tid];
    unsigned char c = (v.x > 0.0f ? 1u : 0u)
                    | (v.y > 0.0f ? 2u : 0u)
                    | (v.z > 0.0f ? 4u : 0u)
                    | (v.w > 0.0f ? 8u : 0u);
    codes[tid] = c;
}

// Pass 2: one thread per output row (b,t,o,r): gather one 64B table row
// (or write zeros for the padded leading timesteps).
__global__ void gather_kernel(const unsigned char* __restrict__ codes,
                              const float* __restrict__ t2,
                              const float* __restrict__ t3,
                              float* __restrict__ out) {
    int tid = blockIdx.x * blockDim.x + threadIdx.x;   // [0, 2^20)
    int r = tid & 255;
    int o = (tid >> 8) & 1;
    int t = (tid >> 9) & 1023;
    int b = tid >> 19;

    float4* dst = reinterpret_cast<float4*>(out) + (size_t)tid * 4;

    const float4* src = nullptr;
    const unsigned char* cb = codes + (size_t)b * TT * RR + r;
    if (o == 0) {
        // 2-gram: t>=1; addr = c[t-1] + 16*c[t]; gidx = r*256 + addr
        if (t >= 1) {
            int c1 = cb[(t - 1) * RR];
            int c0 = cb[t * RR];
            int gidx = (r << 8) + c1 + (c0 << 4);
            src = reinterpret_cast<const float4*>(t2 + (size_t)gidx * DD);
        }
    } else {
        // 3-gram: t>=2; addr = c[t-2] + 16*c[t-1] + 256*c[t]; gidx = r*4096 + addr
        if (t >= 2) {
            int c2 = cb[(t - 2) * RR];
            int c1 = cb[(t - 1) * RR];
            int c0 = cb[t * RR];
            int gidx = (r << 12) + c2 + (c1 << 4) + (c0 << 8);
            src = reinterpret_cast<const float4*>(t3 + (size_t)gidx * DD);
        }
    }

    if (src) {
        float4 a = src[0], b4 = src[1], c4 = src[2], d4 = src[3];
        dst[0] = a; dst[1] = b4; dst[2] = c4; dst[3] = d4;
    } else {
        float4 z = make_float4(0.f, 0.f, 0.f, 0.f);
        dst[0] = z; dst[1] = z; dst[2] = z; dst[3] = z;
    }
}

extern "C" void kernel_launch(void* const* d_in, const int* in_sizes, int n_in,
                              void* d_out, int out_size, void* d_ws, size_t ws_size,
                              hipStream_t stream) {
    const float* q  = (const float*)d_in[0];   // [2,1024,1024] f32
    const float* t2 = (const float*)d_in[1];   // [65536,16] f32
    const float* t3 = (const float*)d_in[2];   // [1048576,16] f32
    float* out = (float*)d_out;                // [2,1024,8192] f32
    unsigned char* codes = (unsigned char*)d_ws; // 512 KiB

    // Pass 1: B*T*R = 524288 codes
    codes_kernel<<<(BB * TT * RR) / 256, 256, 0, stream>>>(q, codes);

    // Pass 2: B*T*2*R = 1048576 rows
    gather_kernel<<<(BB * TT * 2 * RR) / 256, 256, 0, stream>>>(codes, t2, t3, out);
}

// Round 2
// 34.043 us; speedup vs baseline: 1.1726x; 1.1726x over previous
//
#include <hip/hip_runtime.h>

// RouteExactNgramMemory forward.
// Shapes: B=2, T=1024, HIDDEN=1024, BITS=4, R=256 routes, ALPHABET=16,
// MEM_DIM=16, NGRAMS=(2,3).
// out[b,t,o,r,d] flat = [B, T, 2*256*16] f32.

#define BB 2
#define TT 1024
#define RR 256
#define DD 16

using f4 = __attribute__((ext_vector_type(4))) float;

// Pass 1: pack sign bits of 4 consecutive logits into a 4-bit code.
// q viewed as float4[B*T*R]; tid indexes it directly.
__global__ void codes_kernel(const float* __restrict__ q,
                             unsigned char* __restrict__ codes) {
    int tid = blockIdx.x * blockDim.x + threadIdx.x;   // [0, B*T*R)
    f4 v = reinterpret_cast<const f4*>(q)[tid];
    unsigned char c = (v.x > 0.0f ? 1u : 0u)
                    | (v.y > 0.0f ? 2u : 0u)
                    | (v.z > 0.0f ? 4u : 0u)
                    | (v.w > 0.0f ? 8u : 0u);
    codes[tid] = c;
}

// Pass 2: 4 lanes per output row (b,t,o,r). Thread = flat float4 index of out.
// Lane group of 4 reads one contiguous 64B table row (coalesced), stores are
// perfectly contiguous across the wave (64 lanes x 16B = 1KB).
__global__ void gather_kernel(const unsigned char* __restrict__ codes,
                              const float* __restrict__ t2,
                              const float* __restrict__ t3,
                              float* __restrict__ out) {
    int tid = blockIdx.x * blockDim.x + threadIdx.x;   // [0, 2^22)
    int part = tid & 3;            // which float4 of the 64B row
    int row  = tid >> 2;           // [0, 2^20) output row id
    int r = row & 255;
    int o = (row >> 8) & 1;
    int t = (row >> 9) & 1023;
    int b = row >> 19;

    const unsigned char* cb = codes + b * TT * RR + r;

    f4 v = {0.f, 0.f, 0.f, 0.f};
    if (o == 0) {
        // 2-gram: t>=1; addr = c[t-1] + 16*c[t]; gidx = r*256 + addr
        if (t >= 1) {
            int c1 = cb[(t - 1) * RR];
            int c0 = cb[t * RR];
            int gidx = (r << 8) + c1 + (c0 << 4);
            v = reinterpret_cast<const f4*>(t2)[gidx * 4 + part];
        }
    } else {
        // 3-gram: t>=2; addr = c[t-2] + 16*c[t-1] + 256*c[t]; gidx = r*4096 + addr
        if (t >= 2) {
            int c2 = cb[(t - 2) * RR];
            int c1 = cb[(t - 1) * RR];
            int c0 = cb[t * RR];
            int gidx = (r << 12) + c2 + (c1 << 4) + (c0 << 8);
            v = reinterpret_cast<const f4*>(t3)[gidx * 4 + part];
        }
    }

    // Nontemporal: output is write-once, never re-read by us — don't pollute L2.
    __builtin_nontemporal_store(v, reinterpret_cast<f4*>(out) + tid);
}

extern "C" void kernel_launch(void* const* d_in, const int* in_sizes, int n_in,
                              void* d_out, int out_size, void* d_ws, size_t ws_size,
                              hipStream_t stream) {
    const float* q  = (const float*)d_in[0];   // [2,1024,1024] f32
    const float* t2 = (const float*)d_in[1];   // [65536,16] f32
    const float* t3 = (const float*)d_in[2];   // [1048576,16] f32
    float* out = (float*)d_out;                // [2,1024,8192] f32
    unsigned char* codes = (unsigned char*)d_ws; // 512 KiB

    // Pass 1: B*T*R = 524288 codes
    codes_kernel<<<(BB * TT * RR) / 256, 256, 0, stream>>>(q, codes);

    // Pass 2: B*T*2*R*4 = 4194304 threads (4 per 64B output row)
    gather_kernel<<<(BB * TT * 2 * RR * 4) / 256, 256, 0, stream>>>(codes, t2, t3, out);
}

// Round 3
// 30.705 us; speedup vs baseline: 1.3002x; 1.1087x over previous
//
#include <hip/hip_runtime.h>

// RouteExactNgramMemory forward.
// Shapes: B=2, T=1024, HIDDEN=1024, BITS=4, R=256 routes, ALPHABET=16,
// MEM_DIM=16, NGRAMS=(2,3).
// out[b,t,o,r,d] flat = [B, T, 2*256*16] f32.

#define BB 2
#define TT 1024
#define RR 256
#define DD 16

using f4 = __attribute__((ext_vector_type(4))) float;

// Pass 1: pack sign bits of 4 consecutive logits into a 4-bit code.
__global__ void codes_kernel(const float* __restrict__ q,
                             unsigned char* __restrict__ codes) {
    int tid = blockIdx.x * blockDim.x + threadIdx.x;   // [0, B*T*R)
    f4 v = reinterpret_cast<const f4*>(q)[tid];
    unsigned char c = (v.x > 0.0f ? 1u : 0u)
                    | (v.y > 0.0f ? 2u : 0u)
                    | (v.z > 0.0f ? 4u : 0u)
                    | (v.w > 0.0f ? 8u : 0u);
    codes[tid] = c;
}

// Pass 2: each thread produces 4 output float4s: the (o=0,o=1) rows for
// (b, t0, r) and (b, t0+512, r), part `part` of each 64B row.
// -> 4 independent table loads in flight (MLP=4), shared code-byte loads,
//    all stores wave-coalesced (contiguous 1KB per wave per store).
__global__ void gather_kernel(const unsigned char* __restrict__ codes,
                              const float* __restrict__ t2,
                              const float* __restrict__ t3,
                              float* __restrict__ out) {
    int tid = blockIdx.x * blockDim.x + threadIdx.x;   // [0, 2^20)
    int part = tid & 3;
    int r  = (tid >> 2) & 255;
    int t0 = (tid >> 10) & 511;     // wave-uniform
    int b  = tid >> 19;
    int t1 = t0 + 512;              // always >= 2: no edge cases

    const unsigned char* cb = codes + b * TT * RR + r;
    const f4* t2v = reinterpret_cast<const f4*>(t2);
    const f4* t3v = reinterpret_cast<const f4*>(t3);

    // --- codes (L1-resident byte loads, 16 consecutive bytes per wave) ---
    int a0 = cb[t0 * RR];                          // c[t0]
    int a1 = (t0 >= 1) ? cb[(t0 - 1) * RR] : 0;    // c[t0-1]
    int a2 = (t0 >= 2) ? cb[(t0 - 2) * RR] : 0;    // c[t0-2]
    int b0 = cb[t1 * RR];
    int b1 = cb[(t1 - 1) * RR];
    int b2 = cb[(t1 - 2) * RR];

    // --- 4 independent gathers ---
    f4 z = {0.f, 0.f, 0.f, 0.f};
    f4 v00 = z, v01 = z, v10, v11;
    if (t0 >= 1)  // wave-uniform branch
        v00 = t2v[((r << 8) + a1 + (a0 << 4)) * 4 + part];
    if (t0 >= 2)
        v01 = t3v[((r << 12) + a2 + (a1 << 4) + (a0 << 8)) * 4 + part];
    v10 = t2v[((r << 8) + b1 + (b0 << 4)) * 4 + part];
    v11 = t3v[((r << 12) + b2 + (b1 << 4) + (b0 << 8)) * 4 + part];

    // --- coalesced nontemporal stores ---
    // flat f4 index of (b,t,o,r,part) = (((b*TT + t)*2 + o)*RR + r)*4 + part
    f4* ov = reinterpret_cast<f4*>(out);
    size_t base0 = (((size_t)(b * TT + t0) * 2) * RR + r) * 4 + part;
    size_t base1 = (((size_t)(b * TT + t1) * 2) * RR + r) * 4 + part;
    __builtin_nontemporal_store(v00, ov + base0);
    __builtin_nontemporal_store(v01, ov + base0 + RR * 4);
    __builtin_nontemporal_store(v10, ov + base1);
    __builtin_nontemporal_store(v11, ov + base1 + RR * 4);
}

extern "C" void kernel_launch(void* const* d_in, const int* in_sizes, int n_in,
                              void* d_out, int out_size, void* d_ws, size_t ws_size,
                              hipStream_t stream) {
    const float* q  = (const float*)d_in[0];   // [2,1024,1024] f32
    const float* t2 = (const float*)d_in[1];   // [65536,16] f32
    const float* t3 = (const float*)d_in[2];   // [1048576,16] f32
    float* out = (float*)d_out;                // [2,1024,8192] f32
    unsigned char* codes = (unsigned char*)d_ws; // 512 KiB

    // Pass 1: B*T*R = 524288 codes
    codes_kernel<<<(BB * TT * RR) / 256, 256, 0, stream>>>(q, codes);

    // Pass 2: 2^20 threads, 4 output f4s each
    gather_kernel<<<(1 << 20) / 256, 256, 0, stream>>>(codes, t2, t3, out);
}

// Round 4
// 28.251 us; speedup vs baseline: 1.4131x; 1.0869x over previous
//
#include <hip/hip_runtime.h>

// RouteExactNgramMemory forward.
// Shapes: B=2, T=1024, HIDDEN=1024, BITS=4, R=256 routes, ALPHABET=16,
// MEM_DIM=16, NGRAMS=(2,3).
// out[b,t,o,r,d] flat = [B, T, 2*256*16] f32.

#define BB 2
#define TT 1024
#define RR 256
#define DD 16

using f4 = __attribute__((ext_vector_type(4))) float;

// Pass 1: pack sign bits of 4 consecutive logits into a 4-bit code.
__global__ void codes_kernel(const float* __restrict__ q,
                             unsigned char* __restrict__ codes) {
    int tid = blockIdx.x * blockDim.x + threadIdx.x;   // [0, B*T*R)
    f4 v = reinterpret_cast<const f4*>(q)[tid];
    unsigned char c = (v.x > 0.0f ? 1u : 0u)
                    | (v.y > 0.0f ? 2u : 0u)
                    | (v.z > 0.0f ? 4u : 0u)
                    | (v.w > 0.0f ? 8u : 0u);
    codes[tid] = c;
}

// Pass 2: XCD-route-pinned gather.
//   bid = b(1) | tchunk(7) | rgrp(3)   -> bid&7 = route group = XCD id
//   tx  = tlo(1) | rlo(5) | part(2)
// Each thread: 4 t-positions (t0 + 256k) x 2 ngram orders = 8 independent
// 16B gathers in flight; all stores wave-contiguous (1KB/wave/store).
// Per-XCD unique table working set ~3.7MB -> fits 4MB L2; collision
// re-reads become L2 hits.
__global__ void gather_kernel(const unsigned char* __restrict__ codes,
                              const float* __restrict__ t2,
                              const float* __restrict__ t3,
                              float* __restrict__ out) {
    int bid  = blockIdx.x;
    int rgrp = bid & 7;
    int tch  = (bid >> 3) & 127;
    int b    = bid >> 10;
    int tx   = threadIdx.x;
    int part = tx & 3;
    int rlo  = (tx >> 2) & 31;
    int tlo  = tx >> 7;                 // wave-uniform
    int r    = (rgrp << 5) + rlo;
    int t0   = (tch << 1) + tlo;        // [0, 256), wave-uniform

    const unsigned char* cb = codes + b * (TT * RR) + r;
    const f4* t2v = reinterpret_cast<const f4*>(t2);
    const f4* t3v = reinterpret_cast<const f4*>(t3);
    f4* ov = reinterpret_cast<f4*>(out);
    f4 z = {0.f, 0.f, 0.f, 0.f};

    int c0[4], c1[4], c2[4];
#pragma unroll
    for (int k = 0; k < 4; ++k) {
        int t = t0 + k * 256;
        c0[k] = cb[t * RR];
        c1[k] = (t >= 1) ? cb[(t - 1) * RR] : 0;
        c2[k] = (t >= 2) ? cb[(t - 2) * RR] : 0;
    }

    f4 v2[4], v3[4];
#pragma unroll
    for (int k = 0; k < 4; ++k) {
        int t = t0 + k * 256;
        v2[k] = (t >= 1)
            ? t2v[(((r << 8) + c1[k] + (c0[k] << 4)) << 2) + part] : z;
        v3[k] = (t >= 2)
            ? t3v[(((r << 12) + c2[k] + (c1[k] << 4) + (c0[k] << 8)) << 2) + part] : z;
    }

#pragma unroll
    for (int k = 0; k < 4; ++k) {
        int t = t0 + k * 256;
        size_t base = (((size_t)(b * TT + t) * 2) * RR + r) * 4 + part;
        __builtin_nontemporal_store(v2[k], ov + base);
        __builtin_nontemporal_store(v3[k], ov + base + RR * 4);
    }
}

extern "C" void kernel_launch(void* const* d_in, const int* in_sizes, int n_in,
                              void* d_out, int out_size, void* d_ws, size_t ws_size,
                              hipStream_t stream) {
    const float* q  = (const float*)d_in[0];   // [2,1024,1024] f32
    const float* t2 = (const float*)d_in[1];   // [65536,16] f32
    const float* t3 = (const float*)d_in[2];   // [1048576,16] f32
    float* out = (float*)d_out;                // [2,1024,8192] f32
    unsigned char* codes = (unsigned char*)d_ws; // 512 KiB

    // Pass 1: B*T*R = 524288 codes
    codes_kernel<<<(BB * TT * RR) / 256, 256, 0, stream>>>(q, codes);

    // Pass 2: 2048 blocks x 256 threads; 8 gathers/thread
    gather_kernel<<<2048, 256, 0, stream>>>(codes, t2, t3, out);
}

// Round 5
// 23.943 us; speedup vs baseline: 1.6673x; 1.1799x over previous
//
#include <hip/hip_runtime.h>

// RouteExactNgramMemory forward — fully fused single kernel.
// Shapes: B=2, T=1024, HIDDEN=1024, BITS=4, R=256 routes, ALPHABET=16,
// MEM_DIM=16, NGRAMS=(2,3).  out flat = [B, T, 2*256*16] f32.
//
// Block = (b, t-chunk of 8 consecutive t, route-group of 32).
//   bid = b(1) | tchunk(7) | rgrp(3)  -> bid&7 = rgrp = XCD id (L2 pinning:
//   per-XCD unique table slice ~3.8MB fits the 4MB XCD L2).
// Phase 1: block computes the 10x32 codes it needs from q into LDS.
// Phase 2: each thread does 4 t-positions x 2 orders = 8 independent 16B
//   gathers (MLP=8); all stores wave-contiguous nontemporal (1KB/wave).

#define BB 2
#define TT 1024
#define RR 256

using f4 = __attribute__((ext_vector_type(4))) float;

__global__ __launch_bounds__(256) void fused_kernel(
    const float* __restrict__ q,
    const float* __restrict__ t2,
    const float* __restrict__ t3,
    float* __restrict__ out) {
    int bid   = blockIdx.x;
    int rgrp  = bid & 7;
    int tch   = (bid >> 3) & 127;
    int b     = bid >> 10;
    int t0    = tch << 3;          // 8 consecutive t's per block
    int rbase = rgrp << 5;

    __shared__ unsigned char lcode[10 * 32];   // [ti][rlo], t = t0-2+ti

    int tx = threadIdx.x;

    // ---- Phase 1: 320 codes from q (each: one float4 -> 4 sign bits) ----
    const f4* qv = reinterpret_cast<const f4*>(q);   // [B,T,256] f4
#pragma unroll
    for (int i = 0; i < 2; ++i) {
        int item = tx + (i << 8);
        if (item < 320) {
            int ti  = item >> 5;
            int rlo = item & 31;
            int t   = t0 - 2 + ti;
            unsigned char code = 0;
            if (t >= 0) {
                f4 v = qv[(size_t)(b * TT + t) * RR + rbase + rlo];
                code = (v.x > 0.0f ? 1u : 0u)
                     | (v.y > 0.0f ? 2u : 0u)
                     | (v.z > 0.0f ? 4u : 0u)
                     | (v.w > 0.0f ? 8u : 0u);
            }
            lcode[ti * 32 + rlo] = code;
        }
    }
    __syncthreads();

    // ---- Phase 2: gathers ----
    int part = tx & 3;
    int rlo  = (tx >> 2) & 31;
    int tlo  = tx >> 7;            // 0/1, wave-uniform
    int r    = rbase + rlo;

    // 6 consecutive codes for this thread's 4 t's (t = t0 + tlo*4 + k)
    unsigned char cc[6];
#pragma unroll
    for (int j = 0; j < 6; ++j)
        cc[j] = lcode[(tlo * 4 + j) * 32 + rlo];

    const f4* t2v = reinterpret_cast<const f4*>(t2);
    const f4* t3v = reinterpret_cast<const f4*>(t3);
    f4 z = {0.f, 0.f, 0.f, 0.f};
    f4 v2[4], v3[4];
#pragma unroll
    for (int k = 0; k < 4; ++k) {
        int t  = t0 + tlo * 4 + k;         // wave-uniform
        int a2 = cc[k], a1 = cc[k + 1], a0 = cc[k + 2];
        v2[k] = (t >= 1)
            ? t2v[(((r << 8) + a1 + (a0 << 4)) << 2) + part] : z;
        v3[k] = (t >= 2)
            ? t3v[(((r << 12) + a2 + (a1 << 4) + (a0 << 8)) << 2) + part] : z;
    }

    f4* ov = reinterpret_cast<f4*>(out);
#pragma unroll
    for (int k = 0; k < 4; ++k) {
        int t = t0 + tlo * 4 + k;
        size_t base = (((size_t)(b * TT + t) * 2) * RR + r) * 4 + part;
        __builtin_nontemporal_store(v2[k], ov + base);
        __builtin_nontemporal_store(v3[k], ov + base + RR * 4);
    }
}

extern "C" void kernel_launch(void* const* d_in, const int* in_sizes, int n_in,
                              void* d_out, int out_size, void* d_ws, size_t ws_size,
                              hipStream_t stream) {
    const float* q  = (const float*)d_in[0];   // [2,1024,1024] f32
    const float* t2 = (const float*)d_in[1];   // [65536,16] f32
    const float* t3 = (const float*)d_in[2];   // [1048576,16] f32
    float* out = (float*)d_out;                // [2,1024,8192] f32

    // 2 b x 128 t-chunks x 8 route-groups = 2048 blocks
    fused_kernel<<<2048, 256, 0, stream>>>(q, t2, t3, out);
}